// Round 1
// baseline (76124.823 us; speedup 1.0000x reference)
//
#include <hip/hip_runtime.h>
#include <hip/hip_cooperative_groups.h>

namespace cg = cooperative_groups;

static constexpr int   kM      = 2048;
static constexpr int   kN      = 8192;
static constexpr int   kIters  = 1000;
static constexpr float kTau    = 1e-4f;
static constexpr float kSigma  = 1e-4f;
static constexpr int   kBlocks = 256;
static constexpr int   kThreads = 512;                 // 8 waves
static constexpr int   kRowsPerBlk = kM / kBlocks;     // 8  (1 row per wave)
static constexpr int   kColsPerBlk = kN / kBlocks;     // 32 (one 128B line per row)

__global__ __launch_bounds__(kThreads)
void pdhg_solver(const float* __restrict__ cvec,
                 const float* __restrict__ A,
                 const float* __restrict__ bvec,
                 float* __restrict__ out,
                 float* __restrict__ x,
                 float* __restrict__ xbar,
                 float* __restrict__ y)
{
    cg::grid_group grid = cg::this_grid();

    __shared__ float  s_vec[kN];     // phase1: xbar (32 KB); phase2/epilogue: y / relu(-y) (8 KB)
    __shared__ float4 s_part[64];    // cross-wave partials (1 KB)

    const int blk  = blockIdx.x;
    const int tid  = threadIdx.x;
    const int lane = tid & 63;
    const int wv   = tid >> 6;                   // 0..7

    const int mrow = blk * kRowsPerBlk + wv;     // phase-1 row owned by this wave
    const int n0   = blk * kColsPerBlk;          // phase-2 column base owned by block
    const int c4   = tid & 7;                    // float4 column group (0..7)
    const int rsub = tid >> 3;                   // row residue (0..63)

    for (int it = 0; it < kIters; ++it) {
        // ---------- phase 1 : y = min(0, y + sigma*(A@xbar) - sigma*b) ----------
        {
            const float4* src = (const float4*)xbar;
            float4* dst = (float4*)s_vec;
            #pragma unroll
            for (int i = 0; i < (kN / 4) / kThreads; ++i)
                dst[tid + i * kThreads] = src[tid + i * kThreads];
        }
        __syncthreads();
        {
            const float4* Arow = (const float4*)(A + (size_t)mrow * kN);
            const float4* xb4  = (const float4*)s_vec;
            float4 a4 = make_float4(0.f, 0.f, 0.f, 0.f);
            #pragma unroll 8
            for (int i = lane; i < kN / 4; i += 64) {
                float4 a = Arow[i];
                float4 v = xb4[i];
                a4.x = fmaf(a.x, v.x, a4.x);
                a4.y = fmaf(a.y, v.y, a4.y);
                a4.z = fmaf(a.z, v.z, a4.z);
                a4.w = fmaf(a.w, v.w, a4.w);
            }
            float acc = (a4.x + a4.y) + (a4.z + a4.w);
            #pragma unroll
            for (int off = 32; off > 0; off >>= 1)
                acc += __shfl_down(acc, off, 64);
            if (lane == 0) {
                float t = y[mrow] + kSigma * acc - kSigma * bvec[mrow];
                y[mrow] = fminf(0.f, t);
            }
        }
        grid.sync();

        // ---------- phase 2 : x_new = relu(x - tau*(A^T@y) - tau*c); xbar = 2x_new - x ----------
        if (tid < kM / 4)
            ((float4*)s_vec)[tid] = ((const float4*)y)[tid];
        __syncthreads();
        {
            float4 acc = make_float4(0.f, 0.f, 0.f, 0.f);
            #pragma unroll 8
            for (int m = rsub; m < kM; m += 64) {
                float4 a = *(const float4*)(A + (size_t)m * kN + n0 + (c4 << 2));
                float ym = s_vec[m];
                acc.x = fmaf(a.x, ym, acc.x);
                acc.y = fmaf(a.y, ym, acc.y);
                acc.z = fmaf(a.z, ym, acc.z);
                acc.w = fmaf(a.w, ym, acc.w);
            }
            #pragma unroll
            for (int off = 8; off <= 32; off <<= 1) {
                acc.x += __shfl_xor(acc.x, off, 64);
                acc.y += __shfl_xor(acc.y, off, 64);
                acc.z += __shfl_xor(acc.z, off, 64);
                acc.w += __shfl_xor(acc.w, off, 64);
            }
            if (lane < 8) s_part[wv * 8 + c4] = acc;
        }
        __syncthreads();
        if (tid < 8) {
            float4 z = s_part[tid];
            #pragma unroll
            for (int w = 1; w < 8; ++w) {
                float4 p = s_part[w * 8 + tid];
                z.x += p.x; z.y += p.y; z.z += p.z; z.w += p.w;
            }
            const int nn = n0 + tid * 4;
            float4 xo = *(const float4*)(x + nn);
            float4 cc = *(const float4*)(cvec + nn);
            float4 xn;
            xn.x = fmaxf(0.f, xo.x - kTau * z.x - kTau * cc.x);
            xn.y = fmaxf(0.f, xo.y - kTau * z.y - kTau * cc.y);
            xn.z = fmaxf(0.f, xo.z - kTau * z.z - kTau * cc.z);
            xn.w = fmaxf(0.f, xo.w - kTau * z.w - kTau * cc.w);
            float4 xb;
            xb.x = 2.f * xn.x - xo.x;
            xb.y = 2.f * xn.y - xo.y;
            xb.z = 2.f * xn.z - xo.z;
            xb.w = 2.f * xn.w - xo.w;
            *(float4*)(x + nn)    = xn;
            *(float4*)(xbar + nn) = xb;
        }
        grid.sync();
    }

    // ---------- epilogue : out = [x, lam=relu(-y), nu=relu(c - A^T lam)] ----------
    if (lane == 0)
        out[kN + mrow] = fmaxf(0.f, -y[mrow]);        // lam
    if (tid < 8) {
        const int nn = n0 + tid * 4;
        *(float4*)(out + nn) = *(const float4*)(x + nn);   // x
    }
    __syncthreads();
    if (tid < kM / 4) {
        float4 v = ((const float4*)y)[tid];
        float4 w;
        w.x = fmaxf(0.f, -v.x);
        w.y = fmaxf(0.f, -v.y);
        w.z = fmaxf(0.f, -v.z);
        w.w = fmaxf(0.f, -v.w);
        ((float4*)s_vec)[tid] = w;                    // stage lam in LDS
    }
    __syncthreads();
    {
        float4 acc = make_float4(0.f, 0.f, 0.f, 0.f);
        #pragma unroll 8
        for (int m = rsub; m < kM; m += 64) {
            float4 a = *(const float4*)(A + (size_t)m * kN + n0 + (c4 << 2));
            float wm = s_vec[m];
            acc.x = fmaf(a.x, wm, acc.x);
            acc.y = fmaf(a.y, wm, acc.y);
            acc.z = fmaf(a.z, wm, acc.z);
            acc.w = fmaf(a.w, wm, acc.w);
        }
        #pragma unroll
        for (int off = 8; off <= 32; off <<= 1) {
            acc.x += __shfl_xor(acc.x, off, 64);
            acc.y += __shfl_xor(acc.y, off, 64);
            acc.z += __shfl_xor(acc.z, off, 64);
            acc.w += __shfl_xor(acc.w, off, 64);
        }
        if (lane < 8) s_part[wv * 8 + c4] = acc;
    }
    __syncthreads();
    if (tid < 8) {
        float4 z = s_part[tid];
        #pragma unroll
        for (int w = 1; w < 8; ++w) {
            float4 p = s_part[w * 8 + tid];
            z.x += p.x; z.y += p.y; z.z += p.z; z.w += p.w;
        }
        const int nn = n0 + tid * 4;
        float4 cc = *(const float4*)(cvec + nn);
        float4 nu;
        nu.x = fmaxf(0.f, cc.x - z.x);
        nu.y = fmaxf(0.f, cc.y - z.y);
        nu.z = fmaxf(0.f, cc.z - z.z);
        nu.w = fmaxf(0.f, cc.w - z.w);
        *(float4*)(out + kN + kM + nn) = nu;
    }
}

extern "C" void kernel_launch(void* const* d_in, const int* in_sizes, int n_in,
                              void* d_out, int out_size, void* d_ws, size_t ws_size,
                              hipStream_t stream) {
    const float* cvec = (const float*)d_in[0];
    const float* A    = (const float*)d_in[1];
    const float* bvec = (const float*)d_in[2];
    float* out  = (float*)d_out;
    float* ws   = (float*)d_ws;
    float* x    = ws;
    float* xbar = ws + kN;
    float* y    = ws + 2 * kN;

    // zero-init state (ws is re-poisoned to 0xAA before every timed launch)
    hipMemsetAsync(d_ws, 0, (size_t)(2 * kN + kM) * sizeof(float), stream);

    void* args[] = {(void*)&cvec, (void*)&A, (void*)&bvec, (void*)&out,
                    (void*)&x, (void*)&xbar, (void*)&y};
    hipLaunchCooperativeKernel((const void*)pdhg_solver, dim3(kBlocks), dim3(kThreads),
                               args, 0, stream);
}

// Round 5
// 68253.131 us; speedup vs baseline: 1.1153x; 1.1153x over previous
//
#include <hip/hip_runtime.h>
#include <hip/hip_cooperative_groups.h>

namespace cg = cooperative_groups;

typedef _Float16 half8 __attribute__((ext_vector_type(8)));

static constexpr int   kM = 2048, kN = 8192, kIters = 1000;
static constexpr float kTau = 1e-4f, kSigma = 1e-4f;
static constexpr int   kBlocks  = 256;
static constexpr int   kThreads = 1024;               // 16 waves
static constexpr int   kRows = kM / kBlocks;          // 8 rows  per block (fused sweep)
static constexpr int   kCols = kN / kBlocks;          // 32 cols per block (x-update)

// workspace layout (float units)
static constexpr size_t kXbarOff = 0;                                // 8192 floats
static constexpr size_t kPartOff = kN;                               // 256*8192 floats
static constexpr size_t kAhOffF  = kPartOff + (size_t)kBlocks * kN;  // fp16 A from here

__global__ __launch_bounds__(256)
void a_to_fp16(const float* __restrict__ A, _Float16* __restrict__ Ah) {
    const size_t i = ((size_t)blockIdx.x * 256 + threadIdx.x) * 8;
    const float4 a0 = *(const float4*)(A + i);
    const float4 a1 = *(const float4*)(A + i + 4);
    half8 h;
    h[0] = (_Float16)a0.x; h[1] = (_Float16)a0.y; h[2] = (_Float16)a0.z; h[3] = (_Float16)a0.w;
    h[4] = (_Float16)a1.x; h[5] = (_Float16)a1.y; h[6] = (_Float16)a1.z; h[7] = (_Float16)a1.w;
    *(half8*)(Ah + i) = h;
}

__global__ __launch_bounds__(kThreads, 4)
void pdhg_fused(const float* __restrict__ cvec,
                const float* __restrict__ bvec,
                const _Float16* __restrict__ Ah,
                float* __restrict__ xbar,
                float* __restrict__ part,
                float* __restrict__ out)
{
    cg::grid_group grid = cg::this_grid();

    __shared__ float s_dots[kRows][17];   // [row][wave] partial dots (padded)
    __shared__ float s_y[kRows];          // block-local y rows (persistent)
    __shared__ float s_x[kCols];          // block-local x cols (persistent)

    const int blk  = blockIdx.x;
    const int tid  = threadIdx.x;
    const int lane = tid & 63;
    const int wv   = tid >> 6;                 // 0..15
    const int c0   = wv * 512 + lane * 8;      // lane's 8-column base (0..8184)
    const int m0   = blk * kRows;
    const int n0   = blk * kCols;

    if (tid < kRows) s_y[tid] = 0.f;
    if (tid < kCols) s_x[tid] = 0.f;
    __syncthreads();

    const _Float16* aptr = Ah + (size_t)m0 * kN + c0;
    float* pptr = part + (size_t)blk * kN + c0;

    // iterations 0..kIters-1 are PDHG steps; it==kIters is the nu epilogue sweep
    for (int it = 0; it <= kIters; ++it) {
        // ---------- fused A sweep ----------
        half8 a[kRows];
        #pragma unroll
        for (int m = 0; m < kRows; ++m)
            a[m] = *(const half8*)(aptr + (size_t)m * kN);

        if (it < kIters) {
            // dot(A[m,:], xbar) — lane covers its 8 cols, reduce across wave+block
            const float4 xv0 = *(const float4*)(xbar + c0);
            const float4 xv1 = *(const float4*)(xbar + c0 + 4);
            const float xb[8] = {xv0.x, xv0.y, xv0.z, xv0.w, xv1.x, xv1.y, xv1.z, xv1.w};
            #pragma unroll
            for (int m = 0; m < kRows; ++m) {
                float s = 0.f;
                #pragma unroll
                for (int j = 0; j < 8; ++j)
                    s = fmaf((float)a[m][j], xb[j], s);
                #pragma unroll
                for (int off = 32; off > 0; off >>= 1)
                    s += __shfl_xor(s, off, 64);
                if (lane == 0) s_dots[m][wv] = s;
            }
            __syncthreads();
            if (tid < kRows) {
                float s = 0.f;
                #pragma unroll
                for (int w = 0; w < 16; ++w) s += s_dots[tid][w];
                const float t = s_y[tid] + kSigma * s - kSigma * bvec[m0 + tid];
                s_y[tid] = fminf(0.f, t);   // y = min(0, y + sigma*(A@xbar) - sigma*b)
            }
            __syncthreads();
        }

        // weighted column sums: z[n] = sum_m w[m] * A[m,n]  (w = y, or lam for epilogue)
        float w8[kRows];
        #pragma unroll
        for (int m = 0; m < kRows; ++m)
            w8[m] = (it < kIters) ? s_y[m] : fmaxf(0.f, -s_y[m]);

        float z[8] = {0.f, 0.f, 0.f, 0.f, 0.f, 0.f, 0.f, 0.f};
        #pragma unroll
        for (int m = 0; m < kRows; ++m) {
            #pragma unroll
            for (int j = 0; j < 8; ++j)
                z[j] = fmaf(w8[m], (float)a[m][j], z[j]);
        }
        *(float4*)(pptr)     = make_float4(z[0], z[1], z[2], z[3]);
        *(float4*)(pptr + 4) = make_float4(z[4], z[5], z[6], z[7]);

        grid.sync();   // all partials visible

        // ---------- cross-block column reduce + x/xbar (or nu) update ----------
        if (wv < 8) {
            const float* pc = part + n0 + wv * 4;
            float4 acc = make_float4(0.f, 0.f, 0.f, 0.f);
            #pragma unroll
            for (int k = 0; k < 4; ++k) {
                const float4 p = *(const float4*)(pc + (size_t)(lane + 64 * k) * kN);
                acc.x += p.x; acc.y += p.y; acc.z += p.z; acc.w += p.w;
            }
            #pragma unroll
            for (int off = 32; off > 0; off >>= 1) {
                acc.x += __shfl_xor(acc.x, off, 64);
                acc.y += __shfl_xor(acc.y, off, 64);
                acc.z += __shfl_xor(acc.z, off, 64);
                acc.w += __shfl_xor(acc.w, off, 64);
            }
            if (lane == 0) {
                const int nn = n0 + wv * 4;
                const float4 cc = *(const float4*)(cvec + nn);
                if (it < kIters) {
                    const float xo0 = s_x[wv*4+0], xo1 = s_x[wv*4+1];
                    const float xo2 = s_x[wv*4+2], xo3 = s_x[wv*4+3];
                    const float xn0 = fmaxf(0.f, xo0 - kTau*acc.x - kTau*cc.x);
                    const float xn1 = fmaxf(0.f, xo1 - kTau*acc.y - kTau*cc.y);
                    const float xn2 = fmaxf(0.f, xo2 - kTau*acc.z - kTau*cc.z);
                    const float xn3 = fmaxf(0.f, xo3 - kTau*acc.w - kTau*cc.w);
                    s_x[wv*4+0] = xn0; s_x[wv*4+1] = xn1;
                    s_x[wv*4+2] = xn2; s_x[wv*4+3] = xn3;
                    *(float4*)(xbar + nn) =
                        make_float4(2.f*xn0 - xo0, 2.f*xn1 - xo1,
                                    2.f*xn2 - xo2, 2.f*xn3 - xo3);
                } else {
                    // nu = relu(c - A^T lam)
                    *(float4*)(out + kN + kM + nn) =
                        make_float4(fmaxf(0.f, cc.x - acc.x), fmaxf(0.f, cc.y - acc.y),
                                    fmaxf(0.f, cc.z - acc.z), fmaxf(0.f, cc.w - acc.w));
                }
            }
        }
        if (it < kIters) grid.sync();   // xbar visible for next iteration
    }

    // ---------- final outputs: x and lam ----------
    if (tid < kCols) out[n0 + tid] = s_x[tid];                       // x
    if (tid < kRows) out[kN + m0 + tid] = fmaxf(0.f, -s_y[tid]);     // lam = relu(-y)
}

extern "C" void kernel_launch(void* const* d_in, const int* in_sizes, int n_in,
                              void* d_out, int out_size, void* d_ws, size_t ws_size,
                              hipStream_t stream) {
    const float* cvec = (const float*)d_in[0];
    const float* A    = (const float*)d_in[1];
    const float* bvec = (const float*)d_in[2];
    float* out  = (float*)d_out;
    float* ws   = (float*)d_ws;

    float*     xbar = ws + kXbarOff;
    float*     part = ws + kPartOff;
    _Float16*  Ah   = (_Float16*)(ws + kAhOffF);

    // xbar_0 = x_0 = 0 (ws is re-poisoned to 0xAA before every timed launch)
    hipMemsetAsync(xbar, 0, kN * sizeof(float), stream);

    // A -> fp16 workspace copy (runs every launch; ~15 us)
    a_to_fp16<<<dim3((kM * kN / 8) / 256), dim3(256), 0, stream>>>(A, Ah);

    void* args[] = {(void*)&cvec, (void*)&bvec, (void*)&Ah,
                    (void*)&xbar, (void*)&part, (void*)&out};
    hipLaunchCooperativeKernel((const void*)pdhg_fused, dim3(kBlocks), dim3(kThreads),
                               args, 0, stream);
}

// Round 12
// 38898.828 us; speedup vs baseline: 1.9570x; 1.7546x over previous
//
#include <hip/hip_runtime.h>
#include <hip/hip_cooperative_groups.h>

typedef _Float16 half_t;
typedef _Float16 half8 __attribute__((ext_vector_type(8)));

static constexpr int   kM = 2048, kN = 8192, kIters = 1000;
static constexpr float kTau = 1e-4f, kSigma = 1e-4f;
static constexpr int   kBlocks  = 256;
static constexpr int   kThreads = 1024;              // 16 waves
static constexpr int   kRows = kM / kBlocks;         // 8  rows/block  (phase 1)
static constexpr int   kCols = kN / kBlocks;         // 32 cols/block  (phase 2)

// workspace layout (float units)
static constexpr size_t kXbarOff = 0;                // kN floats
static constexpr size_t kYOff    = kN;               // kM floats
static constexpr size_t kCntOff  = kN + kM;          // barrier counter (own 1 KB line)
static constexpr size_t kAtOff   = kN + kM + 256;    // fp16 A^T [kN][kM] from here (~32 MB)

// ---------------- A -> A^T fp16 transpose (runs once per launch) ----------------
__global__ __launch_bounds__(256)
void transpose_fp16(const float* __restrict__ A, half_t* __restrict__ AT) {
    __shared__ float tile[64][65];                   // +1 pad: conflict-free transpose
    const int bid = blockIdx.x;
    const int tm  = bid & 31;                        // kM/64 = 32 tiles along m
    const int tn  = bid >> 5;                        // kN/64 = 128 tiles along n
    const int t   = threadIdx.x;
    const int c   = t & 63;
    const int r0  = t >> 6;                          // 0..3
    #pragma unroll
    for (int k = 0; k < 16; ++k) {
        const int r = k * 4 + r0;
        tile[r][c] = A[(size_t)(tm * 64 + r) * kN + tn * 64 + c];
    }
    __syncthreads();
    #pragma unroll
    for (int k = 0; k < 16; ++k) {
        const int r = k * 4 + r0;                    // row within n-tile
        AT[(size_t)(tn * 64 + r) * kM + tm * 64 + c] = (half_t)tile[c][r];
    }
}

// ---------------- lean grid barrier ----------------
// monotonic counter; ACQ_REL RMW releases this block's writes (flushes dirty L2
// lines to the device coherence point), acquire fence at exit invalidates
// L1/L2 so subsequent plain loads see other XCDs' writes.
__device__ __forceinline__ void gridbar(unsigned* cnt, unsigned g) {
    __syncthreads();
    if (threadIdx.x == 0) {
        __hip_atomic_fetch_add(cnt, 1u, __ATOMIC_ACQ_REL, __HIP_MEMORY_SCOPE_AGENT);
        const unsigned target = g * (unsigned)kBlocks;
        while (__hip_atomic_load(cnt, __ATOMIC_RELAXED, __HIP_MEMORY_SCOPE_AGENT) < target)
            __builtin_amdgcn_s_sleep(1);
        __builtin_amdgcn_fence(__ATOMIC_ACQUIRE, "agent");
    }
    __syncthreads();
}

// ---------------- persistent PDHG kernel ----------------
__global__ __launch_bounds__(kThreads)
void pdhg(const float* __restrict__ cvec,
          const float* __restrict__ bvec,
          const float* __restrict__ A,
          const half_t* __restrict__ AT,
          float* __restrict__ xbar,
          float* __restrict__ yg,
          unsigned* __restrict__ cnt,
          float* __restrict__ out)
{
    __shared__ float s_y[kM];             // staged y (8 KB)
    __shared__ float s_x[kCols];          // block-local x (persistent)
    __shared__ float s_ymine[kRows];      // block-local y rows (persistent)
    __shared__ float s_dot[kRows][2];     // phase-1 per-row half-sums
    __shared__ float s_z[kCols];          // phase-2 per-col sums

    const int tid  = threadIdx.x;
    const int lane = tid & 63;
    const int wv   = tid >> 6;            // 0..15
    const int blk  = blockIdx.x;
    const int m0   = blk * kRows;
    const int n0   = blk * kCols;

    if (tid < kRows) s_ymine[tid] = 0.f;
    if (tid < kCols) s_x[tid] = 0.f;
    __syncthreads();

    // phase-1 geometry: wave wv -> row (wv>>1), half (wv&1) of kN
    const float* Arow = A + (size_t)(m0 + (wv >> 1)) * kN + (size_t)(wv & 1) * (kN / 2);
    // phase-2 geometry: wave wv -> cols {2wv, 2wv+1}; 32-lane group per col
    const int   cidx  = 2 * wv + (lane >> 5);    // 0..31
    const int   sub   = lane & 31;
    const half_t* ATrow = AT + (size_t)(n0 + cidx) * kM;

    unsigned g = 0;

    for (int it = 0; it < kIters; ++it) {
        // -------- phase 1: y[m] = min(0, y + sigma*dot(A[m,:],xbar) - sigma*b[m]) --------
        {
            const float* xb = xbar + (size_t)(wv & 1) * (kN / 2);
            float acc = 0.f;
            #pragma unroll
            for (int k = 0; k < 8; ++k) {
                const int o = k * 512 + lane * 8;
                const float4 a0 = *(const float4*)(Arow + o);
                const float4 a1 = *(const float4*)(Arow + o + 4);
                const float4 x0 = *(const float4*)(xb + o);
                const float4 x1 = *(const float4*)(xb + o + 4);
                acc = fmaf(a0.x, x0.x, acc); acc = fmaf(a0.y, x0.y, acc);
                acc = fmaf(a0.z, x0.z, acc); acc = fmaf(a0.w, x0.w, acc);
                acc = fmaf(a1.x, x1.x, acc); acc = fmaf(a1.y, x1.y, acc);
                acc = fmaf(a1.z, x1.z, acc); acc = fmaf(a1.w, x1.w, acc);
            }
            #pragma unroll
            for (int off = 32; off > 0; off >>= 1)
                acc += __shfl_xor(acc, off, 64);
            if (lane == 0) s_dot[wv >> 1][wv & 1] = acc;
        }
        __syncthreads();
        if (tid < kRows) {
            const float dot = s_dot[tid][0] + s_dot[tid][1];
            const float t = s_ymine[tid] + kSigma * dot - kSigma * bvec[m0 + tid];
            const float yn = fminf(0.f, t);
            s_ymine[tid] = yn;
            yg[m0 + tid] = yn;
        }
        gridbar(cnt, ++g);

        // -------- phase 2: z[n] = dot(AT[n,:], y); x,xbar update --------
        s_y[tid]        = yg[tid];
        s_y[tid + 1024] = yg[tid + 1024];
        __syncthreads();
        {
            float acc = 0.f;
            #pragma unroll
            for (int k = 0; k < 8; ++k) {
                const int o = k * 256 + sub * 8;
                const half8 a = *(const half8*)(ATrow + o);
                acc = fmaf((float)a[0], s_y[o + 0], acc);
                acc = fmaf((float)a[1], s_y[o + 1], acc);
                acc = fmaf((float)a[2], s_y[o + 2], acc);
                acc = fmaf((float)a[3], s_y[o + 3], acc);
                acc = fmaf((float)a[4], s_y[o + 4], acc);
                acc = fmaf((float)a[5], s_y[o + 5], acc);
                acc = fmaf((float)a[6], s_y[o + 6], acc);
                acc = fmaf((float)a[7], s_y[o + 7], acc);
            }
            #pragma unroll
            for (int off = 16; off > 0; off >>= 1)
                acc += __shfl_xor(acc, off, 64);   // reduce within 32-lane group
            if (sub == 0) s_z[cidx] = acc;
        }
        __syncthreads();
        if (tid < kCols) {
            const float z  = s_z[tid];
            const float xo = s_x[tid];
            const float xn = fmaxf(0.f, xo - kTau * z - kTau * cvec[n0 + tid]);
            s_x[tid] = xn;
            xbar[n0 + tid] = 2.f * xn - xo;
        }
        if (it + 1 < kIters) gridbar(cnt, ++g);  // xbar visible for next phase 1
    }

    // -------- epilogue: out = [x, lam=relu(-y), nu=relu(c - A^T lam)] --------
    __syncthreads();                                  // protect s_z reuse
    if (tid < kCols) out[n0 + tid] = s_x[tid];                       // x
    if (tid < kRows) out[kN + m0 + tid] = fmaxf(0.f, -s_ymine[tid]); // lam
    // s_y still holds the final y (staged in last phase 2)
    {
        float acc = 0.f;
        #pragma unroll
        for (int k = 0; k < 8; ++k) {
            const int o = k * 256 + sub * 8;
            const half8 a = *(const half8*)(ATrow + o);
            acc = fmaf((float)a[0], fmaxf(0.f, -s_y[o + 0]), acc);
            acc = fmaf((float)a[1], fmaxf(0.f, -s_y[o + 1]), acc);
            acc = fmaf((float)a[2], fmaxf(0.f, -s_y[o + 2]), acc);
            acc = fmaf((float)a[3], fmaxf(0.f, -s_y[o + 3]), acc);
            acc = fmaf((float)a[4], fmaxf(0.f, -s_y[o + 4]), acc);
            acc = fmaf((float)a[5], fmaxf(0.f, -s_y[o + 5]), acc);
            acc = fmaf((float)a[6], fmaxf(0.f, -s_y[o + 6]), acc);
            acc = fmaf((float)a[7], fmaxf(0.f, -s_y[o + 7]), acc);
        }
        #pragma unroll
        for (int off = 16; off > 0; off >>= 1)
            acc += __shfl_xor(acc, off, 64);
        if (sub == 0) s_z[cidx] = acc;
    }
    __syncthreads();
    if (tid < kCols)
        out[kN + kM + n0 + tid] = fmaxf(0.f, cvec[n0 + tid] - s_z[tid]);  // nu
}

extern "C" void kernel_launch(void* const* d_in, const int* in_sizes, int n_in,
                              void* d_out, int out_size, void* d_ws, size_t ws_size,
                              hipStream_t stream) {
    const float* cvec = (const float*)d_in[0];
    const float* A    = (const float*)d_in[1];
    const float* bvec = (const float*)d_in[2];
    float* out = (float*)d_out;
    float* ws  = (float*)d_ws;

    float*    xbar = ws + kXbarOff;
    float*    yg   = ws + kYOff;
    unsigned* cnt  = (unsigned*)(ws + kCntOff);
    half_t*   AT   = (half_t*)(ws + kAtOff);

    // zero xbar, y, barrier counter (ws re-poisoned to 0xAA before every launch)
    hipMemsetAsync(ws, 0, (kCntOff + 256) * sizeof(float), stream);

    // build fp16 A^T (4096 blocks x 256 threads, ~30 us)
    transpose_fp16<<<dim3((kM / 64) * (kN / 64)), dim3(256), 0, stream>>>(A, AT);

    void* args[] = {(void*)&cvec, (void*)&bvec, (void*)&A, (void*)&AT,
                    (void*)&xbar, (void*)&yg, (void*)&cnt, (void*)&out};
    hipLaunchCooperativeKernel((const void*)pdhg, dim3(kBlocks), dim3(kThreads),
                               args, 0, stream);
}

// Round 13
// 28648.026 us; speedup vs baseline: 2.6572x; 1.3578x over previous
//
#include <hip/hip_runtime.h>

typedef _Float16 half_t;
typedef _Float16 half8 __attribute__((ext_vector_type(8)));

static constexpr int   kM = 2048, kN = 8192, kIters = 1000;
static constexpr float kTau = 1e-4f, kSigma = 1e-4f;
static constexpr int   kBlocks  = 256;
static constexpr int   kThreads = 1024;              // 16 waves
static constexpr int   kRows = kM / kBlocks;         // 8  rows/block  (phase 1)
static constexpr int   kCols = kN / kBlocks;         // 32 cols/block  (phase 2)

// workspace layout (float units)
static constexpr size_t kXbarOff = 0;                            // kN
static constexpr size_t kYOff    = kN;                           // kM
static constexpr size_t kGoOff   = kN + kM;                      // 16 (go flag, own line)
static constexpr size_t kArrOff  = kGoOff + 16;                  // 256 slots x 16 floats (64B pad)
static constexpr size_t kAtOffF  = kArrOff + (size_t)kBlocks*16; // fp16 A^T [kN][kM] (32 MB)
static constexpr size_t kAhOffF  = kAtOffF + (size_t)kM*kN/2;    // fp16 A  [kM][kN] (32 MB, optional)
static constexpr size_t kEndBaseF = kAhOffF;                     // variant B end
static constexpr size_t kEndFullF = kAhOffF + (size_t)kM*kN/2;   // variant A end

// ---------------- A -> A^T fp16 transpose ----------------
__global__ __launch_bounds__(256)
void transpose_fp16(const float* __restrict__ A, half_t* __restrict__ AT) {
    __shared__ float tile[64][65];
    const int bid = blockIdx.x;
    const int tm  = bid & 31;
    const int tn  = bid >> 5;
    const int t   = threadIdx.x;
    const int c   = t & 63;
    const int r0  = t >> 6;
    #pragma unroll
    for (int k = 0; k < 16; ++k) {
        const int r = k * 4 + r0;
        tile[r][c] = A[(size_t)(tm * 64 + r) * kN + tn * 64 + c];
    }
    __syncthreads();
    #pragma unroll
    for (int k = 0; k < 16; ++k) {
        const int r = k * 4 + r0;
        AT[(size_t)(tn * 64 + r) * kM + tm * 64 + c] = (half_t)tile[c][r];
    }
}

// ---------------- A -> fp16 row-major copy ----------------
__global__ __launch_bounds__(256)
void a_to_fp16(const float* __restrict__ A, half_t* __restrict__ Ah) {
    const size_t i = ((size_t)blockIdx.x * 256 + threadIdx.x) * 8;
    const float4 a0 = *(const float4*)(A + i);
    const float4 a1 = *(const float4*)(A + i + 4);
    half8 h;
    h[0] = (half_t)a0.x; h[1] = (half_t)a0.y; h[2] = (half_t)a0.z; h[3] = (half_t)a0.w;
    h[4] = (half_t)a1.x; h[5] = (half_t)a1.y; h[6] = (half_t)a1.z; h[7] = (half_t)a1.w;
    *(half8*)(Ah + i) = h;
}

// ---------------- parallel-arrival grid barrier ----------------
// arrivals: parallel release-stores to padded slots; master (block 0) polls all
// slots with 255 lanes in parallel, acquire-fences, release-stores `go`;
// everyone else polls `go` then acquire-fences. ~2 round-trips total.
__device__ __forceinline__ void gridbar(unsigned* go, unsigned* arr, unsigned g) {
    __syncthreads();
    if (blockIdx.x == 0) {
        if (threadIdx.x < kBlocks - 1) {
            while (__hip_atomic_load(&arr[(threadIdx.x + 1) * 16],
                                     __ATOMIC_RELAXED, __HIP_MEMORY_SCOPE_AGENT) < g)
                __builtin_amdgcn_s_sleep(1);
        }
        __syncthreads();                    // all 255 peer arrivals observed
        if (threadIdx.x == 0) {
            __builtin_amdgcn_fence(__ATOMIC_ACQUIRE, "agent");   // transitive edge
            __hip_atomic_store(go, g, __ATOMIC_RELEASE, __HIP_MEMORY_SCOPE_AGENT);
        }
    } else {
        if (threadIdx.x == 0) {
            __hip_atomic_store(&arr[blockIdx.x * 16], g,
                               __ATOMIC_RELEASE, __HIP_MEMORY_SCOPE_AGENT);
            while (__hip_atomic_load(go, __ATOMIC_RELAXED, __HIP_MEMORY_SCOPE_AGENT) < g)
                __builtin_amdgcn_s_sleep(1);
            __builtin_amdgcn_fence(__ATOMIC_ACQUIRE, "agent");
        }
    }
    __syncthreads();
}

// ---------------- persistent PDHG kernel ----------------
// s_yp uses swizzled index i + (i>>5): phase-2's per-lane reads at stride 8
// then land in 32 distinct banks (conflict-free).
template <bool FP16A>
__global__ __launch_bounds__(kThreads)
void pdhg(const float* __restrict__ cvec,
          const float* __restrict__ bvec,
          const float* __restrict__ A,
          const half_t* __restrict__ Ah,
          const half_t* __restrict__ AT,
          float* __restrict__ xbar,
          float* __restrict__ yg,
          unsigned* __restrict__ go,
          unsigned* __restrict__ arr,
          float* __restrict__ out)
{
    __shared__ float s_yp[kM + kM / 32];  // swizzled staged y (8.25 KB)
    __shared__ float s_x[kCols];
    __shared__ float s_ymine[kRows];
    __shared__ float s_dot[kRows][2];
    __shared__ float s_z[kCols];

    const int tid  = threadIdx.x;
    const int lane = tid & 63;
    const int wv   = tid >> 6;            // 0..15
    const int blk  = blockIdx.x;
    const int m0   = blk * kRows;
    const int n0   = blk * kCols;

    if (tid < kRows) s_ymine[tid] = 0.f;
    if (tid < kCols) s_x[tid] = 0.f;
    __syncthreads();

    // phase-1: wave wv -> row (wv>>1), half (wv&1) of kN
    const float*  Arow  = A  + (size_t)(m0 + (wv >> 1)) * kN + (size_t)(wv & 1) * (kN / 2);
    const half_t* ArowH = Ah + (size_t)(m0 + (wv >> 1)) * kN + (size_t)(wv & 1) * (kN / 2);
    // phase-2: wave wv -> cols {2wv, 2wv+1}; 32-lane group per col
    const int   cidx  = 2 * wv + (lane >> 5);
    const int   sub   = lane & 31;
    const int   ybase = sub * 8 + (sub >> 2);        // swizzled per-lane base
    const half_t* ATrow = AT + (size_t)(n0 + cidx) * kM;

    unsigned g = 0;

    for (int it = 0; it < kIters; ++it) {
        // -------- phase 1: y = min(0, y + sigma*(A@xbar) - sigma*b) --------
        {
            const float* xb = xbar + (size_t)(wv & 1) * (kN / 2);
            float acc = 0.f;
            #pragma unroll
            for (int k = 0; k < 8; ++k) {
                const int o = k * 512 + lane * 8;
                const float4 x0 = *(const float4*)(xb + o);
                const float4 x1 = *(const float4*)(xb + o + 4);
                if (FP16A) {
                    const half8 a = *(const half8*)(ArowH + o);
                    acc = fmaf((float)a[0], x0.x, acc); acc = fmaf((float)a[1], x0.y, acc);
                    acc = fmaf((float)a[2], x0.z, acc); acc = fmaf((float)a[3], x0.w, acc);
                    acc = fmaf((float)a[4], x1.x, acc); acc = fmaf((float)a[5], x1.y, acc);
                    acc = fmaf((float)a[6], x1.z, acc); acc = fmaf((float)a[7], x1.w, acc);
                } else {
                    const float4 a0 = *(const float4*)(Arow + o);
                    const float4 a1 = *(const float4*)(Arow + o + 4);
                    acc = fmaf(a0.x, x0.x, acc); acc = fmaf(a0.y, x0.y, acc);
                    acc = fmaf(a0.z, x0.z, acc); acc = fmaf(a0.w, x0.w, acc);
                    acc = fmaf(a1.x, x1.x, acc); acc = fmaf(a1.y, x1.y, acc);
                    acc = fmaf(a1.z, x1.z, acc); acc = fmaf(a1.w, x1.w, acc);
                }
            }
            #pragma unroll
            for (int off = 32; off > 0; off >>= 1)
                acc += __shfl_xor(acc, off, 64);
            if (lane == 0) s_dot[wv >> 1][wv & 1] = acc;
        }
        __syncthreads();
        if (tid < kRows) {
            const float dot = s_dot[tid][0] + s_dot[tid][1];
            const float t = s_ymine[tid] + kSigma * dot - kSigma * bvec[m0 + tid];
            const float yn = fminf(0.f, t);
            s_ymine[tid] = yn;
            yg[m0 + tid] = yn;
        }
        gridbar(go, arr, ++g);

        // -------- phase 2: z[n] = dot(AT[n,:], y); x,xbar update --------
        {
            const int i1 = tid, i2 = tid + 1024;
            s_yp[i1 + (i1 >> 5)] = yg[i1];
            s_yp[i2 + (i2 >> 5)] = yg[i2];
        }
        __syncthreads();
        {
            float acc = 0.f;
            #pragma unroll
            for (int k = 0; k < 8; ++k) {
                const half8 a = *(const half8*)(ATrow + k * 256 + sub * 8);
                const int p = k * 264 + ybase;
                acc = fmaf((float)a[0], s_yp[p + 0], acc);
                acc = fmaf((float)a[1], s_yp[p + 1], acc);
                acc = fmaf((float)a[2], s_yp[p + 2], acc);
                acc = fmaf((float)a[3], s_yp[p + 3], acc);
                acc = fmaf((float)a[4], s_yp[p + 4], acc);
                acc = fmaf((float)a[5], s_yp[p + 5], acc);
                acc = fmaf((float)a[6], s_yp[p + 6], acc);
                acc = fmaf((float)a[7], s_yp[p + 7], acc);
            }
            #pragma unroll
            for (int off = 16; off > 0; off >>= 1)
                acc += __shfl_xor(acc, off, 64);
            if (sub == 0) s_z[cidx] = acc;
        }
        __syncthreads();
        if (tid < kCols) {
            const float z  = s_z[tid];
            const float xo = s_x[tid];
            const float xn = fmaxf(0.f, xo - kTau * z - kTau * cvec[n0 + tid]);
            s_x[tid] = xn;
            xbar[n0 + tid] = 2.f * xn - xo;
        }
        if (it + 1 < kIters) gridbar(go, arr, ++g);
    }

    // -------- epilogue: out = [x, lam=relu(-y), nu=relu(c - A^T lam)] --------
    __syncthreads();
    if (tid < kCols) out[n0 + tid] = s_x[tid];
    if (tid < kRows) out[kN + m0 + tid] = fmaxf(0.f, -s_ymine[tid]);
    {
        float acc = 0.f;
        #pragma unroll
        for (int k = 0; k < 8; ++k) {
            const half8 a = *(const half8*)(ATrow + k * 256 + sub * 8);
            const int p = k * 264 + ybase;
            acc = fmaf((float)a[0], fmaxf(0.f, -s_yp[p + 0]), acc);
            acc = fmaf((float)a[1], fmaxf(0.f, -s_yp[p + 1]), acc);
            acc = fmaf((float)a[2], fmaxf(0.f, -s_yp[p + 2]), acc);
            acc = fmaf((float)a[3], fmaxf(0.f, -s_yp[p + 3]), acc);
            acc = fmaf((float)a[4], fmaxf(0.f, -s_yp[p + 4]), acc);
            acc = fmaf((float)a[5], fmaxf(0.f, -s_yp[p + 5]), acc);
            acc = fmaf((float)a[6], fmaxf(0.f, -s_yp[p + 6]), acc);
            acc = fmaf((float)a[7], fmaxf(0.f, -s_yp[p + 7]), acc);
        }
        #pragma unroll
        for (int off = 16; off > 0; off >>= 1)
            acc += __shfl_xor(acc, off, 64);
        if (sub == 0) s_z[cidx] = acc;
    }
    __syncthreads();
    if (tid < kCols)
        out[kN + kM + n0 + tid] = fmaxf(0.f, cvec[n0 + tid] - s_z[tid]);
}

extern "C" void kernel_launch(void* const* d_in, const int* in_sizes, int n_in,
                              void* d_out, int out_size, void* d_ws, size_t ws_size,
                              hipStream_t stream) {
    const float* cvec = (const float*)d_in[0];
    const float* A    = (const float*)d_in[1];
    const float* bvec = (const float*)d_in[2];
    float* out = (float*)d_out;
    float* ws  = (float*)d_ws;

    float*    xbar = ws + kXbarOff;
    float*    yg   = ws + kYOff;
    unsigned* go   = (unsigned*)(ws + kGoOff);
    unsigned* arr  = (unsigned*)(ws + kArrOff);
    half_t*   AT   = (half_t*)(ws + kAtOffF);
    half_t*   Ah   = (half_t*)(ws + kAhOffF);

    const bool fp16rows = ws_size >= kEndFullF * sizeof(float);

    // zero xbar, yg, go, arr (ws re-poisoned to 0xAA before every launch)
    hipMemsetAsync(ws, 0, kAtOffF * sizeof(float), stream);

    transpose_fp16<<<dim3((kM / 64) * (kN / 64)), dim3(256), 0, stream>>>(A, AT);
    if (fp16rows)
        a_to_fp16<<<dim3((kM * kN / 8) / 256), dim3(256), 0, stream>>>(A, Ah);

    void* args[] = {(void*)&cvec, (void*)&bvec, (void*)&A, (void*)&Ah, (void*)&AT,
                    (void*)&xbar, (void*)&yg, (void*)&go, (void*)&arr, (void*)&out};
    const void* kfn = fp16rows ? (const void*)&pdhg<true> : (const void*)&pdhg<false>;
    hipLaunchCooperativeKernel(kfn, dim3(kBlocks), dim3(kThreads), args, 0, stream);
}

// Round 15
// 16026.767 us; speedup vs baseline: 4.7499x; 1.7875x over previous
//
#include <hip/hip_runtime.h>

typedef _Float16 half_t;
typedef _Float16 half8 __attribute__((ext_vector_type(8)));
typedef float f32x4 __attribute__((ext_vector_type(4)));

static constexpr int   kM = 2048, kN = 8192, kIters = 1000;
static constexpr float kTau = 1e-4f, kSigma = 1e-4f;
static constexpr int   kBlocks  = 256;
static constexpr int   kThreads = 1024;              // 16 waves
static constexpr int   kRows = kM / kBlocks;         // 8  rows/block  (phase 1)
static constexpr int   kCols = kN / kBlocks;         // 32 cols/block  (phase 2)

// workspace layout (float units)
static constexpr size_t kXbarOff = 0;                            // kN
static constexpr size_t kYOff    = kN;                           // kM
static constexpr size_t kGoOff   = kN + kM;                      // 32 (own 128B line)
static constexpr size_t kArrOff  = kGoOff + 32;                  // 256 slots x 32 floats
static constexpr size_t kAtOffF  = kArrOff + (size_t)kBlocks*32; // fp16 A^T (32 MB)
static constexpr size_t kAhOffF  = kAtOffF + (size_t)kM*kN/2;    // fp16 A   (32 MB)
static constexpr size_t kEndFullF = kAhOffF + (size_t)kM*kN/2;

// ---------------- coherent (L1/L2-bypassing) access helpers ----------------
__device__ __forceinline__ void ld8_cohere(const float* p, f32x4& a, f32x4& b) {
    asm volatile("global_load_dwordx4 %0, %2, off sc0 sc1\n\t"
                 "global_load_dwordx4 %1, %2, off offset:16 sc0 sc1\n\t"
                 "s_waitcnt vmcnt(0)"
                 : "=&v"(a), "=&v"(b) : "v"(p) : "memory");
}
__device__ __forceinline__ void ld2_cohere(const float* p0, const float* p1,
                                           float& v0, float& v1) {
    asm volatile("global_load_dword %0, %2, off sc0 sc1\n\t"
                 "global_load_dword %1, %3, off sc0 sc1\n\t"
                 "s_waitcnt vmcnt(0)"
                 : "=&v"(v0), "=&v"(v1) : "v"(p0), "v"(p1) : "memory");
}
__device__ __forceinline__ void st_cohere(float* p, float v) {
    asm volatile("global_store_dword %0, %1, off sc0 sc1"
                 :: "v"(p), "v"(v) : "memory");
}

// ---------------- A -> A^T fp16 transpose ----------------
__global__ __launch_bounds__(256)
void transpose_fp16(const float* __restrict__ A, half_t* __restrict__ AT) {
    __shared__ float tile[64][65];
    const int bid = blockIdx.x;
    const int tm  = bid & 31;
    const int tn  = bid >> 5;
    const int t   = threadIdx.x;
    const int c   = t & 63;
    const int r0  = t >> 6;
    #pragma unroll
    for (int k = 0; k < 16; ++k) {
        const int r = k * 4 + r0;
        tile[r][c] = A[(size_t)(tm * 64 + r) * kN + tn * 64 + c];
    }
    __syncthreads();
    #pragma unroll
    for (int k = 0; k < 16; ++k) {
        const int r = k * 4 + r0;
        AT[(size_t)(tn * 64 + r) * kM + tm * 64 + c] = (half_t)tile[c][r];
    }
}

// ---------------- A -> fp16 row-major copy ----------------
__global__ __launch_bounds__(256)
void a_to_fp16(const float* __restrict__ A, half_t* __restrict__ Ah) {
    const size_t i = ((size_t)blockIdx.x * 256 + threadIdx.x) * 8;
    const float4 a0 = *(const float4*)(A + i);
    const float4 a1 = *(const float4*)(A + i + 4);
    half8 h;
    h[0] = (half_t)a0.x; h[1] = (half_t)a0.y; h[2] = (half_t)a0.z; h[3] = (half_t)a0.w;
    h[4] = (half_t)a1.x; h[5] = (half_t)a1.y; h[6] = (half_t)a1.z; h[7] = (half_t)a1.w;
    *(half8*)(Ah + i) = h;
}

// ---------------- fence-free grid barrier ----------------
// All atomics RELAXED (no buffer_wbl2 / buffer_inv). Data moves via sc0+sc1
// write-through stores, drained to the coherence point by the vmcnt(0) that
// __syncthreads() implies, BEFORE the arrival store issues. Readers use
// sc0+sc1 loads, so no cache invalidation is ever needed.
__device__ __forceinline__ void gridbar(unsigned* go, unsigned* arr, unsigned g) {
    __syncthreads();
    if (blockIdx.x == 0) {
        if (threadIdx.x < kBlocks - 1) {
            while (__hip_atomic_load(&arr[(threadIdx.x + 1) * 32],
                                     __ATOMIC_RELAXED, __HIP_MEMORY_SCOPE_AGENT) < g)
                __builtin_amdgcn_s_sleep(1);
        }
        __syncthreads();                    // all 255 peer arrivals observed
        if (threadIdx.x == 0)
            __hip_atomic_store(go, g, __ATOMIC_RELAXED, __HIP_MEMORY_SCOPE_AGENT);
    } else {
        if (threadIdx.x == 0) {
            __hip_atomic_store(&arr[blockIdx.x * 32], g,
                               __ATOMIC_RELAXED, __HIP_MEMORY_SCOPE_AGENT);
            while (__hip_atomic_load(go, __ATOMIC_RELAXED, __HIP_MEMORY_SCOPE_AGENT) < g)
                __builtin_amdgcn_s_sleep(1);
        }
    }
    __syncthreads();
}

// ---------------- persistent PDHG kernel ----------------
template <bool FP16A>
__global__ __launch_bounds__(kThreads)
void pdhg(const float* __restrict__ cvec,
          const float* __restrict__ bvec,
          const float* __restrict__ A,
          const half_t* __restrict__ Ah,
          const half_t* __restrict__ AT,
          float* __restrict__ xbar,
          float* __restrict__ yg,
          unsigned* __restrict__ go,
          unsigned* __restrict__ arr,
          float* __restrict__ out)
{
    __shared__ float s_xb[kN];            // staged xbar (32 KB)
    __shared__ float s_yp[kM + kM / 32];  // swizzled staged y (8.25 KB)
    __shared__ float s_x[kCols];
    __shared__ float s_ymine[kRows];
    __shared__ float s_dot[kRows][2];
    __shared__ float s_z[kCols];

    const int tid  = threadIdx.x;
    const int lane = tid & 63;
    const int wv   = tid >> 6;            // 0..15
    const int blk  = blockIdx.x;
    const int m0   = blk * kRows;
    const int n0   = blk * kCols;

    if (tid < kRows) s_ymine[tid] = 0.f;
    if (tid < kCols) s_x[tid] = 0.f;

    // phase-1: wave wv -> row (wv>>1), half (wv&1) of kN; A/Ah loads stay CACHED
    const float*  Arow  = A  + (size_t)(m0 + (wv >> 1)) * kN + (size_t)(wv & 1) * (kN / 2);
    const half_t* ArowH = Ah + (size_t)(m0 + (wv >> 1)) * kN + (size_t)(wv & 1) * (kN / 2);
    // phase-2: wave wv -> cols {2wv, 2wv+1}; 32-lane group per col; AT CACHED
    const int   cidx  = 2 * wv + (lane >> 5);
    const int   sub   = lane & 31;
    const int   ybase = sub * 8 + (sub >> 2);
    const half_t* ATrow = AT + (size_t)(n0 + cidx) * kM;

    unsigned g = 0;

    for (int it = 0; it < kIters; ++it) {
        // -------- stage xbar -> LDS (coherent reads; 8 floats/thread) --------
        {
            f32x4 a, b;
            ld8_cohere(xbar + tid * 8, a, b);
            *(f32x4*)&s_xb[tid * 8]     = a;
            *(f32x4*)&s_xb[tid * 8 + 4] = b;
        }
        __syncthreads();

        // -------- phase 1: y = min(0, y + sigma*(A@xbar) - sigma*b) --------
        {
            const float* xb = s_xb + (size_t)(wv & 1) * (kN / 2);
            float acc = 0.f;
            #pragma unroll
            for (int k = 0; k < 8; ++k) {
                const int o = k * 512 + lane * 8;
                const float4 x0 = *(const float4*)(xb + o);
                const float4 x1 = *(const float4*)(xb + o + 4);
                if (FP16A) {
                    const half8 a = *(const half8*)(ArowH + o);
                    acc = fmaf((float)a[0], x0.x, acc); acc = fmaf((float)a[1], x0.y, acc);
                    acc = fmaf((float)a[2], x0.z, acc); acc = fmaf((float)a[3], x0.w, acc);
                    acc = fmaf((float)a[4], x1.x, acc); acc = fmaf((float)a[5], x1.y, acc);
                    acc = fmaf((float)a[6], x1.z, acc); acc = fmaf((float)a[7], x1.w, acc);
                } else {
                    const float4 a0 = *(const float4*)(Arow + o);
                    const float4 a1 = *(const float4*)(Arow + o + 4);
                    acc = fmaf(a0.x, x0.x, acc); acc = fmaf(a0.y, x0.y, acc);
                    acc = fmaf(a0.z, x0.z, acc); acc = fmaf(a0.w, x0.w, acc);
                    acc = fmaf(a1.x, x1.x, acc); acc = fmaf(a1.y, x1.y, acc);
                    acc = fmaf(a1.z, x1.z, acc); acc = fmaf(a1.w, x1.w, acc);
                }
            }
            #pragma unroll
            for (int off = 32; off > 0; off >>= 1)
                acc += __shfl_xor(acc, off, 64);
            if (lane == 0) s_dot[wv >> 1][wv & 1] = acc;
        }
        __syncthreads();
        if (tid < kRows) {
            const float dot = s_dot[tid][0] + s_dot[tid][1];
            const float t = s_ymine[tid] + kSigma * dot - kSigma * bvec[m0 + tid];
            const float yn = fminf(0.f, t);
            s_ymine[tid] = yn;
            st_cohere(yg + m0 + tid, yn);
        }
        gridbar(go, arr, ++g);

        // -------- stage y -> LDS swizzled (coherent reads; 2 floats/thread) --------
        {
            float v0, v1;
            ld2_cohere(yg + tid, yg + tid + 1024, v0, v1);
            const int i1 = tid, i2 = tid + 1024;
            s_yp[i1 + (i1 >> 5)] = v0;
            s_yp[i2 + (i2 >> 5)] = v1;
        }
        __syncthreads();

        // -------- phase 2: z[n] = dot(AT[n,:], y); x,xbar update --------
        {
            float acc = 0.f;
            #pragma unroll
            for (int k = 0; k < 8; ++k) {
                const half8 a = *(const half8*)(ATrow + k * 256 + sub * 8);
                const int p = k * 264 + ybase;
                acc = fmaf((float)a[0], s_yp[p + 0], acc);
                acc = fmaf((float)a[1], s_yp[p + 1], acc);
                acc = fmaf((float)a[2], s_yp[p + 2], acc);
                acc = fmaf((float)a[3], s_yp[p + 3], acc);
                acc = fmaf((float)a[4], s_yp[p + 4], acc);
                acc = fmaf((float)a[5], s_yp[p + 5], acc);
                acc = fmaf((float)a[6], s_yp[p + 6], acc);
                acc = fmaf((float)a[7], s_yp[p + 7], acc);
            }
            #pragma unroll
            for (int off = 16; off > 0; off >>= 1)
                acc += __shfl_xor(acc, off, 64);
            if (sub == 0) s_z[cidx] = acc;
        }
        __syncthreads();
        if (tid < kCols) {
            const float z  = s_z[tid];
            const float xo = s_x[tid];
            const float xn = fmaxf(0.f, xo - kTau * z - kTau * cvec[n0 + tid]);
            s_x[tid] = xn;
            st_cohere(xbar + n0 + tid, 2.f * xn - xo);
        }
        if (it + 1 < kIters) gridbar(go, arr, ++g);
    }

    // -------- epilogue: out = [x, lam=relu(-y), nu=relu(c - A^T lam)] --------
    __syncthreads();
    if (tid < kCols) out[n0 + tid] = s_x[tid];
    if (tid < kRows) out[kN + m0 + tid] = fmaxf(0.f, -s_ymine[tid]);
    {
        float acc = 0.f;
        #pragma unroll
        for (int k = 0; k < 8; ++k) {
            const half8 a = *(const half8*)(ATrow + k * 256 + sub * 8);
            const int p = k * 264 + ybase;
            acc = fmaf((float)a[0], fmaxf(0.f, -s_yp[p + 0]), acc);
            acc = fmaf((float)a[1], fmaxf(0.f, -s_yp[p + 1]), acc);
            acc = fmaf((float)a[2], fmaxf(0.f, -s_yp[p + 2]), acc);
            acc = fmaf((float)a[3], fmaxf(0.f, -s_yp[p + 3]), acc);
            acc = fmaf((float)a[4], fmaxf(0.f, -s_yp[p + 4]), acc);
            acc = fmaf((float)a[5], fmaxf(0.f, -s_yp[p + 5]), acc);
            acc = fmaf((float)a[6], fmaxf(0.f, -s_yp[p + 6]), acc);
            acc = fmaf((float)a[7], fmaxf(0.f, -s_yp[p + 7]), acc);
        }
        #pragma unroll
        for (int off = 16; off > 0; off >>= 1)
            acc += __shfl_xor(acc, off, 64);
        if (sub == 0) s_z[cidx] = acc;
    }
    __syncthreads();
    if (tid < kCols)
        out[kN + kM + n0 + tid] = fmaxf(0.f, cvec[n0 + tid] - s_z[tid]);
}

extern "C" void kernel_launch(void* const* d_in, const int* in_sizes, int n_in,
                              void* d_out, int out_size, void* d_ws, size_t ws_size,
                              hipStream_t stream) {
    const float* cvec = (const float*)d_in[0];
    const float* A    = (const float*)d_in[1];
    const float* bvec = (const float*)d_in[2];
    float* out = (float*)d_out;
    float* ws  = (float*)d_ws;

    float*    xbar = ws + kXbarOff;
    float*    yg   = ws + kYOff;
    unsigned* go   = (unsigned*)(ws + kGoOff);
    unsigned* arr  = (unsigned*)(ws + kArrOff);
    half_t*   AT   = (half_t*)(ws + kAtOffF);
    half_t*   Ah   = (half_t*)(ws + kAhOffF);

    const bool fp16rows = ws_size >= kEndFullF * sizeof(float);

    // zero xbar, yg, go, arr (ws re-poisoned to 0xAA before every launch)
    hipMemsetAsync(ws, 0, kAtOffF * sizeof(float), stream);

    transpose_fp16<<<dim3((kM / 64) * (kN / 64)), dim3(256), 0, stream>>>(A, AT);
    if (fp16rows)
        a_to_fp16<<<dim3((kM * kN / 8) / 256), dim3(256), 0, stream>>>(A, Ah);

    void* args[] = {(void*)&cvec, (void*)&bvec, (void*)&A, (void*)&Ah, (void*)&AT,
                    (void*)&xbar, (void*)&yg, (void*)&go, (void*)&arr, (void*)&out};
    const void* kfn = fp16rows ? (const void*)&pdhg<true> : (const void*)&pdhg<false>;
    hipLaunchCooperativeKernel(kfn, dim3(kBlocks), dim3(kThreads), args, 0, stream);
}